// Round 4
// baseline (541.932 us; speedup 1.0000x reference)
//
#include <hip/hip_runtime.h>
#include <math.h>

#define D 768
#define NPROTO 20
#define NLDS 10                 // protos staged in LDS
#define NGLB (NPROTO - NLDS)    // protos read from global (L1/L2-hot)
#define NCLS 13
#define D4 (D / 4)              // 192 float4 per row
#define NK (D4 / 4)             // 48 k-chunks (4 lanes/row, one float4 each)

__device__ __forceinline__ float dot4f(const float4 a, const float4 b) {
    return a.x * b.x + a.y * b.y + a.z * b.z + a.w * b.w;
}

// sum over aligned 4-lane quads via DPP quad_perm (VALU pipe, no LDS traffic)
__device__ __forceinline__ float quad_red(float v) {
    v += __int_as_float(__builtin_amdgcn_update_dpp(
        0, __float_as_int(v), 0xB1, 0xF, 0xF, true));   // xor 1
    v += __int_as_float(__builtin_amdgcn_update_dpp(
        0, __float_as_int(v), 0x4E, 0xF, 0xF, true));   // xor 2
    return v;
}

// ws layout (floats): [0, 15360) protos_norm [20][768]; [15360, 15620) logits [20][13]

// One block per prototype. Numerics identical to rounds 1-3 (passed) prep.
__global__ __launch_bounds__(256) void proto_prep(
    const float* __restrict__ prototypes,
    const int* __restrict__ role_id,
    const float* __restrict__ W,
    const float* __restrict__ bvec,
    float* __restrict__ ws)
{
    const int p = blockIdx.x;            // 0..19
    const int tid = threadIdx.x;
    const int wave = tid >> 6;
    const int lane = tid & 63;

    const float4* src = reinterpret_cast<const float4*>(
        prototypes + ((size_t)role_id[0] * NPROTO + p) * D);
    float4 v[3];
    #pragma unroll
    for (int j = 0; j < 3; ++j) v[j] = src[lane + 64 * j];

    float ss = 0.f;
    #pragma unroll
    for (int j = 0; j < 3; ++j) ss += dot4f(v[j], v[j]);
    #pragma unroll
    for (int s = 1; s < 64; s <<= 1) ss += __shfl_xor(ss, s, 64);
    const float nrm = fmaxf(sqrtf(ss), 1e-12f);

    float4 nv[3];
    #pragma unroll
    for (int j = 0; j < 3; ++j) {
        nv[j].x = v[j].x / nrm; nv[j].y = v[j].y / nrm;
        nv[j].z = v[j].z / nrm; nv[j].w = v[j].w / nrm;
    }
    if (wave == 0) {
        float4* dst = reinterpret_cast<float4*>(ws + (size_t)p * D);
        #pragma unroll
        for (int j = 0; j < 3; ++j) dst[lane + 64 * j] = nv[j];
    }

    for (int r = wave; r < NCLS; r += 4) {
        const float4* wr = reinterpret_cast<const float4*>(W + (size_t)r * D);
        float a = 0.f;
        #pragma unroll
        for (int j = 0; j < 3; ++j) a += dot4f(nv[j], wr[lane + 64 * j]);
        #pragma unroll
        for (int s = 1; s < 64; s <<= 1) a += __shfl_xor(a, s, 64);
        if (lane == 0) ws[NPROTO * D + p * NCLS + r] = a + bvec[r];
    }
}

// 4 lanes per row, 2 rows per quad -> 32 rows per wave, 128 per block,
// grid 1024 = 4 blocks/CU = 4 waves/SIMD. Protos 0..9 from LDS (broadcast),
// 10..19 from global ws (L1/L2-resident, 30.7 KB). Per-row math identical
// to round 3 (same per-sub k-order, same quad_red tree, same p scan order).
__global__ __launch_bounds__(256, 4) void proto_main(
    const float* __restrict__ x,
    const float* __restrict__ ws,
    float* __restrict__ out_min,
    float* __restrict__ out_pred)
{
    __shared__ float pl[NLDS * D];          // 30720 B
    __shared__ float lgs[NPROTO * NCLS];    // 1040 B
    const int tid = threadIdx.x;

    {   // stage 10 protos (1920 float4) + logits
        const float4* src = reinterpret_cast<const float4*>(ws);
        float4* dst = reinterpret_cast<float4*>(pl);
        #pragma unroll
        for (int k = 0; k < 7; ++k) dst[tid + 256 * k] = src[tid + 256 * k];
        if (tid < 128) dst[1792 + tid] = src[1792 + tid];
        lgs[tid] = ws[NPROTO * D + tid];
        if (tid < NPROTO * NCLS - 256) lgs[256 + tid] = ws[NPROTO * D + 256 + tid];
    }
    __syncthreads();

    const int wave = tid >> 6;
    const int lane = tid & 63;
    const int quad = lane >> 2;     // 0..15
    const int sub  = lane & 3;      // float4 slot within a 4-float4 chunk
    const int row0 = blockIdx.x * 128 + wave * 32 + quad * 2;

    const float4* xr0 = reinterpret_cast<const float4*>(x + (size_t)(row0 + 0) * D) + sub;
    const float4* xr1 = reinterpret_cast<const float4*>(x + (size_t)(row0 + 1) * D) + sub;
    const float4* gp  = reinterpret_cast<const float4*>(ws + (size_t)NLDS * D) + sub;
    const float4* pl4 = reinterpret_cast<const float4*>(pl);

    float acc[NPROTO][2];
    #pragma unroll
    for (int p = 0; p < NPROTO; ++p) { acc[p][0] = 0.f; acc[p][1] = 0.f; }
    float ssx[2] = {0.f, 0.f};

    float4 xa[2], xb[2];
    xa[0] = xr0[0]; xa[1] = xr1[0];

    for (int k = 0; k < NK; k += 2) {
        // prefetch x chunk k+1 (NK even -> always exists)
        xb[0] = xr0[4 * (k + 1)]; xb[1] = xr1[4 * (k + 1)];

        {   // compute chunk k
            float4 pg[NGLB];
            #pragma unroll
            for (int q = 0; q < NGLB; ++q) pg[q] = gp[q * D4 + 4 * k];
            const float4* pp = pl4 + 4 * k + sub;
            #pragma unroll
            for (int p = 0; p < NLDS; ++p) {
                const float4 pv = pp[p * D4];
                acc[p][0] += dot4f(xa[0], pv);
                acc[p][1] += dot4f(xa[1], pv);
            }
            ssx[0] += dot4f(xa[0], xa[0]);
            ssx[1] += dot4f(xa[1], xa[1]);
            #pragma unroll
            for (int q = 0; q < NGLB; ++q) {
                acc[NLDS + q][0] += dot4f(xa[0], pg[q]);
                acc[NLDS + q][1] += dot4f(xa[1], pg[q]);
            }
        }

        if (k + 2 < NK) {   // prefetch x chunk k+2
            xa[0] = xr0[4 * (k + 2)]; xa[1] = xr1[4 * (k + 2)];
        }

        {   // compute chunk k+1
            float4 pg[NGLB];
            #pragma unroll
            for (int q = 0; q < NGLB; ++q) pg[q] = gp[q * D4 + 4 * (k + 1)];
            const float4* pp = pl4 + 4 * (k + 1) + sub;
            #pragma unroll
            for (int p = 0; p < NLDS; ++p) {
                const float4 pv = pp[p * D4];
                acc[p][0] += dot4f(xb[0], pv);
                acc[p][1] += dot4f(xb[1], pv);
            }
            ssx[0] += dot4f(xb[0], xb[0]);
            ssx[1] += dot4f(xb[1], xb[1]);
            #pragma unroll
            for (int q = 0; q < NGLB; ++q) {
                acc[NLDS + q][0] += dot4f(xb[0], pg[q]);
                acc[NLDS + q][1] += dot4f(xb[1], pg[q]);
            }
        }
    }

    #pragma unroll
    for (int r = 0; r < 2; ++r) {
        const float ss = quad_red(ssx[r]);
        const float inv = 1.0f / fmaxf(sqrtf(ss), 1e-12f);

        // np-order scan in dist space (strict > keeps first index on ties)
        float best = 0.f; int bidx = 0;
        #pragma unroll
        for (int p = 0; p < NPROTO; ++p) {
            const float sim = quad_red(acc[p][r]) * inv;
            const float u = expf(sim) / 10.0f;
            const float dcur = 1.0f / (1.0f + u);
            if (p == 0) best = dcur;
            else if (dcur > best) { best = dcur; bidx = p; }
        }

        const int row = row0 + r;
        if (sub == 0) out_min[row] = best;
        #pragma unroll
        for (int m = 0; m < 4; ++m) {
            const int c = sub + 4 * m;
            if (c < NCLS) out_pred[(size_t)row * NCLS + c] = lgs[bidx * NCLS + c];
        }
    }
}

extern "C" void kernel_launch(void* const* d_in, const int* in_sizes, int n_in,
                              void* d_out, int out_size, void* d_ws, size_t ws_size,
                              hipStream_t stream) {
    const float* x          = (const float*)d_in[0];   // [B, 768]
    const int*   role_id    = (const int*)d_in[1];     // scalar
    const float* prototypes = (const float*)d_in[2];   // [260, 768]
    const float* W          = (const float*)d_in[3];   // [13, 768]
    const float* b          = (const float*)d_in[4];   // [13]
    float* out = (float*)d_out;
    float* ws  = (float*)d_ws;

    const int B = in_sizes[0] / D;                     // 131072

    proto_prep<<<NPROTO, 256, 0, stream>>>(prototypes, role_id, W, b, ws);
    proto_main<<<B / 128, 256, 0, stream>>>(x, ws, out, out + B);
}